// Round 1
// 836.262 us; speedup vs baseline: 1.1321x; 1.1321x over previous
//
#include <hip/hip_runtime.h>
#include <hip/hip_bf16.h>
#include <math.h>

#define TILE 128
#define BK 32

using short8  = __attribute__((ext_vector_type(8))) short;
using short4v = __attribute__((ext_vector_type(4))) short;
using f32x4   = __attribute__((ext_vector_type(4))) float;
typedef __hip_bfloat16 bf16;

constexpr int BB = 8, SEQ = 2048, C = 1024, H3 = 3072, DH = 512, MH = 2048;
constexpr int MR = BB * SEQ;  // 16384 token rows

enum {
  F_TRANSB = 1,   // B given as [N,K] row-major
  F_GELU   = 2,
  F_RES    = 4,
  F_OUTBF16= 8,
  F_BIAS   = 16,
  F_SCALE  = 32,
  F_RESF32 = 64
};

struct ZOffs { long long a[16]; long long b[16]; long long c[16]; };

__device__ __forceinline__ float bf2f(bf16 h) { return __bfloat162float(h); }

// async global->LDS, 16B per lane; LDS dest is wave-uniform base + lane*16
__device__ __forceinline__ void gload16(const void* g, void* l) {
  __builtin_amdgcn_global_load_lds(
      (const __attribute__((address_space(1))) unsigned int*)g,
      (__attribute__((address_space(3))) unsigned int*)l, 16, 0, 0);
}

// ---------------------------------------------------------------------------
// OLD 128x128 GEMM (kept only for the no-Vt fallback PV path, B=[K,N] layout)
// ---------------------------------------------------------------------------
template<int FLAGS>
__global__ __launch_bounds__(256) void gemm_k(
    const bf16* __restrict__ A,
    const bf16* __restrict__ B,
    void* __restrict__ Dst,
    const float* __restrict__ bias,
    const void* __restrict__ res,
    int K, int lda, int ldb, int ldc,
    float scale, ZOffs zo)
{
  __shared__ __align__(16) unsigned short As[TILE * BK];
  __shared__ __align__(16) unsigned short Bs[TILE * BK];
  const int tid = threadIdx.x;
  const int z = blockIdx.z;
  const int m0 = blockIdx.y * TILE, n0 = blockIdx.x * TILE;
  const bf16* Ab = A + zo.a[z];
  const bf16* Bb = B + zo.b[z];
  const long long coff = zo.c[z];
  const int wave = tid >> 6, lane = tid & 63;
  const int wm = (wave & 1) << 6, wn = (wave >> 1) << 6;
  const int lr = lane & 15, lq = lane >> 4;

  int srow[2], skb[2];
  #pragma unroll
  for (int i = 0; i < 2; i++) {
    int c = tid + (i << 8);
    srow[i] = c >> 2;
    skb[i]  = (c & 3) ^ ((srow[i] >> 1) & 3);
  }
  const bf16* Asrc[2]; const bf16* Bsrc[2] = {nullptr, nullptr};
  #pragma unroll
  for (int i = 0; i < 2; i++)
    Asrc[i] = Ab + (size_t)(m0 + srow[i]) * lda + skb[i] * 8;
  if (FLAGS & F_TRANSB) {
    #pragma unroll
    for (int i = 0; i < 2; i++)
      Bsrc[i] = Bb + (size_t)(n0 + srow[i]) * ldb + skb[i] * 8;
  }

  f32x4 acc[4][4] = {};
  const int swl = (lr >> 1) & 3;

  for (int k0 = 0; k0 < K; k0 += BK) {
    #pragma unroll
    for (int i = 0; i < 2; i++)
      gload16(Asrc[i] + k0, &As[(tid + (i << 8)) * 8]);
    if (FLAGS & F_TRANSB) {
      #pragma unroll
      for (int i = 0; i < 2; i++)
        gload16(Bsrc[i] + k0, &Bs[(tid + (i << 8)) * 8]);
    } else {
      #pragma unroll
      for (int i = 0; i < 2; i++) {
        int c = tid + (i << 8);
        int kk = c >> 4, nn = (c & 15) << 3;
        unsigned short tmp[8];
        *(uint4*)tmp = *(const uint4*)(Bb + (size_t)(k0 + kk) * ldb + n0 + nn);
        #pragma unroll
        for (int j = 0; j < 8; j++) {
          int n = nn + j;
          Bs[n * BK + (((kk >> 3) ^ ((n >> 1) & 3)) << 3) + (kk & 7)] = tmp[j];
        }
      }
    }
    __syncthreads();
    short8 af[4], bfr[4];
    #pragma unroll
    for (int mi = 0; mi < 4; mi++)
      af[mi] = *(const short8*)&As[(wm + mi * 16 + lr) * BK + ((lq ^ swl) << 3)];
    #pragma unroll
    for (int ni = 0; ni < 4; ni++)
      bfr[ni] = *(const short8*)&Bs[(wn + ni * 16 + lr) * BK + ((lq ^ swl) << 3)];
    #pragma unroll
    for (int mi = 0; mi < 4; mi++)
      #pragma unroll
      for (int ni = 0; ni < 4; ni++)
        acc[mi][ni] = __builtin_amdgcn_mfma_f32_16x16x32_bf16(
            af[mi], bfr[ni], acc[mi][ni], 0, 0, 0);
    __syncthreads();
  }

  #pragma unroll
  for (int mi = 0; mi < 4; mi++) {
    #pragma unroll
    for (int ni = 0; ni < 4; ni++) {
      int col = n0 + wn + ni * 16 + lr;
      float bv = (FLAGS & F_BIAS) ? bias[col] : 0.0f;
      #pragma unroll
      for (int r = 0; r < 4; r++) {
        int row = m0 + wm + mi * 16 + lq * 4 + r;
        float v = acc[mi][ni][r];
        if (FLAGS & F_SCALE) v *= scale;
        v += bv;
        if (FLAGS & F_GELU) v = 0.5f * v * (1.0f + erff(v * 0.70710678118654752f));
        if (FLAGS & F_RES) {
          size_t ridx = (size_t)row * ldc + col;
          v += (FLAGS & F_RESF32) ? ((const float*)res)[ridx]
                                  : bf2f(((const bf16*)res)[ridx]);
        }
        size_t idx = (size_t)coff + (size_t)row * ldc + col;
        if (FLAGS & F_OUTBF16) ((bf16*)Dst)[idx] = __float2bfloat16(v);
        else                   ((float*)Dst)[idx] = v;
      }
    }
  }
}

// ---------------------------------------------------------------------------
// NEW 256x256 deep-pipelined GEMM (T3+T4+T5): BK=32, 512 threads = 8 waves
// (2 M x 4 N), per-wave 128x64 output. 4 LDS K-tile buffers (128 KiB), loads
// issued 3 tiles ahead, counted s_waitcnt vmcnt(8) at tile boundaries (never
// 0 in steady state), raw s_barrier, setprio(1) around MFMA clusters.
// Requires F_TRANSB (B as [N,K]) and M,N % 256 == 0, K % 32 == 0.
// ---------------------------------------------------------------------------
template<int FLAGS>
__global__ __launch_bounds__(512, 2) void gemm256_k(
    const bf16* __restrict__ A,
    const bf16* __restrict__ B,
    void* __restrict__ Dst,
    const float* __restrict__ bias,
    const void* __restrict__ res,
    int K, int lda, int ldb, int ldc,
    float scale, ZOffs zo)
{
  static_assert(FLAGS & F_TRANSB, "gemm256_k requires B^T layout");
  extern __shared__ __align__(16) unsigned short smem[];
  unsigned short* AsAll = smem;                    // 4 bufs * 256*32 ushorts
  unsigned short* BsAll = smem + 4 * 256 * 32;

  const int tid = threadIdx.x;
  const int z = blockIdx.z;
  const int m0 = blockIdx.y * 256, n0 = blockIdx.x * 256;
  const bf16* Ab = A + zo.a[z];
  const bf16* Bb = B + zo.b[z];
  const long long coff = zo.c[z];
  const int wave = tid >> 6, lane = tid & 63;
  const int wm = wave >> 2, wn = wave & 3;         // 2 x 4 wave grid
  const int lr = lane & 15, lq = lane >> 4;
  const int swl = (lr >> 1) & 3;
  const int kcol = (lq ^ swl) << 3;                // swizzled k element offset

  // staging: chunk c = tid + i*512, c in [0,1024): row=c>>2, dest slot=c&3,
  // source k-slot = (c&3) ^ ((row>>1)&3)  (XOR swizzle via pre-swizzled src)
  const bf16* Asrc[2]; const bf16* Bsrc[2];
  #pragma unroll
  for (int i = 0; i < 2; i++) {
    int c = tid + (i << 9);
    int row = c >> 2;
    int ks  = (c & 3) ^ ((row >> 1) & 3);
    Asrc[i] = Ab + (size_t)(m0 + row) * lda + ks * 8;
    Bsrc[i] = Bb + (size_t)(n0 + row) * ldb + ks * 8;
  }
  const int d0 = tid * 8, d1 = (tid + 512) * 8;    // LDS dest (ushort idx)

  const int nt = K >> 5;                           // K-tiles of 32

  // prologue: stage tiles 0..2 (FIFO order A0,A1,B0,B1 per tile)
  const int npro = nt < 3 ? nt : 3;
  for (int t = 0; t < npro; ++t) {
    unsigned short* At_ = AsAll + (t & 3) * 8192;
    unsigned short* Bt_ = BsAll + (t & 3) * 8192;
    const int k0 = t * 32;
    gload16(Asrc[0] + k0, At_ + d0);
    gload16(Asrc[1] + k0, At_ + d1);
    gload16(Bsrc[0] + k0, Bt_ + d0);
    gload16(Bsrc[1] + k0, Bt_ + d1);
  }

  f32x4 acc[8][4] = {};
  short8 af[4], bfr[2];

#define RD_A(mh_)                                                            \
  _Pragma("unroll")                                                          \
  for (int m_ = 0; m_ < 4; ++m_)                                             \
    af[m_] = *(const short8*)&At[(wm * 128 + (mh_) * 64 + m_ * 16 + lr) * 32 + kcol];

#define RD_B(nh_)                                                            \
  _Pragma("unroll")                                                          \
  for (int n_ = 0; n_ < 2; ++n_)                                             \
    bfr[n_] = *(const short8*)&Bt[(wn * 64 + (nh_) * 32 + n_ * 16 + lr) * 32 + kcol];

#define MM(mh_, nh_)                                                         \
  __builtin_amdgcn_s_setprio(1);                                             \
  _Pragma("unroll")                                                          \
  for (int m_ = 0; m_ < 4; ++m_)                                             \
    _Pragma("unroll")                                                        \
    for (int n_ = 0; n_ < 2; ++n_)                                           \
      acc[(mh_) * 4 + m_][(nh_) * 2 + n_] =                                  \
          __builtin_amdgcn_mfma_f32_16x16x32_bf16(                           \
              af[m_], bfr[n_], acc[(mh_) * 4 + m_][(nh_) * 2 + n_], 0, 0, 0);\
  __builtin_amdgcn_s_setprio(0);

  for (int t = 0; t < nt; ++t) {
    // tile-boundary wait: tile t's 4 loads/thread retired; keep up to 2
    // future tiles (8 loads) in flight. Counted vmcnt -- never drains the
    // prefetch queue in steady state.
    const int ahead = nt - 1 - t;
    if (ahead >= 2)      asm volatile("s_waitcnt vmcnt(8)" ::: "memory");
    else if (ahead == 1) asm volatile("s_waitcnt vmcnt(4)" ::: "memory");
    else                 asm volatile("s_waitcnt vmcnt(0)" ::: "memory");
    __builtin_amdgcn_s_barrier();

    const unsigned short* At = AsAll + (t & 3) * 8192;
    const unsigned short* Bt = BsAll + (t & 3) * 8192;
    const int ts = t + 3;
    const bool st = ts < nt;                       // stage tile t+3
    unsigned short* Ad = AsAll + (ts & 3) * 8192;
    unsigned short* Bd = BsAll + (ts & 3) * 8192;
    const int ks0 = ts * 32;

    // phase 0: quadrant (mh=0, nh=0)
    RD_A(0); RD_B(0);
    if (st) gload16(Asrc[0] + ks0, Ad + d0);
    __builtin_amdgcn_s_barrier();
    MM(0, 0);
    __builtin_amdgcn_s_barrier();

    // phase 1: (0, 1) -- af reused
    RD_B(1);
    if (st) gload16(Asrc[1] + ks0, Ad + d1);
    __builtin_amdgcn_s_barrier();
    MM(0, 1);
    __builtin_amdgcn_s_barrier();

    // phase 2: (1, 1) -- bfr reused
    RD_A(1);
    if (st) gload16(Bsrc[0] + ks0, Bd + d0);
    __builtin_amdgcn_s_barrier();
    MM(1, 1);
    __builtin_amdgcn_s_barrier();

    // phase 3: (1, 0)
    RD_B(0);
    if (st) gload16(Bsrc[1] + ks0, Bd + d1);
    __builtin_amdgcn_s_barrier();
    MM(1, 0);
    __builtin_amdgcn_s_barrier();
  }

#undef RD_A
#undef RD_B
#undef MM

  // epilogue: C/D layout col=lane&15, row=quad*4+reg
  const int colBase = n0 + wn * 64 + lr;
  float bv[4];
  #pragma unroll
  for (int n = 0; n < 4; ++n)
    bv[n] = (FLAGS & F_BIAS) ? bias[colBase + n * 16] : 0.0f;
  #pragma unroll
  for (int m = 0; m < 8; ++m) {
    #pragma unroll
    for (int n = 0; n < 4; ++n) {
      const int col = colBase + n * 16;
      #pragma unroll
      for (int r = 0; r < 4; ++r) {
        const int row = m0 + wm * 128 + m * 16 + lq * 4 + r;
        float v = acc[m][n][r];
        if (FLAGS & F_SCALE) v *= scale;
        v += bv[n];
        if (FLAGS & F_GELU) v = 0.5f * v * (1.0f + erff(v * 0.70710678118654752f));
        if (FLAGS & F_RES) {
          size_t ridx = (size_t)row * ldc + col;
          v += (FLAGS & F_RESF32) ? ((const float*)res)[ridx]
                                  : bf2f(((const bf16*)res)[ridx]);
        }
        size_t idx = (size_t)coff + (size_t)row * ldc + col;
        if (FLAGS & F_OUTBF16) ((bf16*)Dst)[idx] = __float2bfloat16(v);
        else                   ((float*)Dst)[idx] = v;
      }
    }
  }
}

// ---------- weight transpose+convert: src fp32 [K,N] -> dst bf16 [N,K] ----------
__global__ __launch_bounds__(256) void tconv_kernel(
    const float* __restrict__ src, bf16* __restrict__ dst, int K, int N)
{
  __shared__ float t[32][33];
  int n0 = blockIdx.x * 32, k0 = blockIdx.y * 32;
  int c = threadIdx.x & 31, r = threadIdx.x >> 5;
  #pragma unroll
  for (int i = 0; i < 4; i++)
    t[r + i * 8][c] = src[(size_t)(k0 + r + i * 8) * N + n0 + c];
  __syncthreads();
  #pragma unroll
  for (int i = 0; i < 4; i++)
    dst[(size_t)(n0 + r + i * 8) * K + k0 + c] = __float2bfloat16(t[c][r + i * 8]);
}

// ---------- V transpose: qkv V-slice [n][d] -> Vt[bh][d][n] (bf16) ----------
__global__ __launch_bounds__(256) void vtrans_kernel(
    const bf16* __restrict__ qkv, bf16* __restrict__ vt)
{
  __shared__ unsigned short t[32][33];
  int bh = blockIdx.z, b = bh >> 1, h = bh & 1;
  int n0 = blockIdx.x * 32, d0 = blockIdx.y * 32;
  int c = threadIdx.x & 31, r = threadIdx.x >> 5;
  const bf16* src = qkv + (size_t)b * SEQ * H3 + 2 * C + (size_t)h * DH;
  #pragma unroll
  for (int i = 0; i < 4; i++)
    t[r + i * 8][c] = *(const unsigned short*)&src[(size_t)(n0 + r + i * 8) * H3 + d0 + c];
  __syncthreads();
  bf16* dst = vt + ((size_t)bh * DH + d0) * SEQ + n0;
  #pragma unroll
  for (int i = 0; i < 4; i++)
    *(unsigned short*)&dst[(size_t)(r + i * 8) * SEQ + c] = t[c][r + i * 8];
}

// ---------- vectorized loads for LN ----------
__device__ __forceinline__ void ld4(const float* p, float v[4]) {
  const float4 t = *(const float4*)p;
  v[0] = t.x; v[1] = t.y; v[2] = t.z; v[3] = t.w;
}
__device__ __forceinline__ void ld4(const bf16* p, float v[4]) {
  short4v t = *(const short4v*)p;
  #pragma unroll
  for (int i = 0; i < 4; ++i) v[i] = bf2f(((const bf16*)&t)[i]);
}

// ---------- LayerNorm over C=1024, one block per row (vectorized) ----------
template<typename T>
__global__ __launch_bounds__(256) void ln_kernel(
    const T* __restrict__ x,
    const float* __restrict__ w,
    const float* __restrict__ b,
    bf16* __restrict__ out)
{
  __shared__ float sm[4], sm2[4];
  int row = blockIdx.x, tid = threadIdx.x;
  float v[4];
  ld4(x + (size_t)row * 1024 + tid * 4, v);
  float s  = v[0] + v[1] + v[2] + v[3];
  float sq = v[0]*v[0] + v[1]*v[1] + v[2]*v[2] + v[3]*v[3];
  #pragma unroll
  for (int o = 32; o > 0; o >>= 1) {
    s  += __shfl_down(s, o, 64);
    sq += __shfl_down(sq, o, 64);
  }
  int wvi = tid >> 6, lnn = tid & 63;
  if (lnn == 0) { sm[wvi] = s; sm2[wvi] = sq; }
  __syncthreads();
  s  = sm[0] + sm[1] + sm[2] + sm[3];
  sq = sm2[0] + sm2[1] + sm2[2] + sm2[3];
  float mean = s * (1.0f / 1024.0f);
  float var  = sq * (1.0f / 1024.0f) - mean * mean;
  float rs = rsqrtf(var + 1e-5f);
  float wv4[4], bv4[4];
  ld4(w + tid * 4, wv4);
  ld4(b + tid * 4, bv4);
  short4v o4;
  #pragma unroll
  for (int i = 0; i < 4; ++i)
    ((bf16*)&o4)[i] = __float2bfloat16((v[i] - mean) * rs * wv4[i] + bv4[i]);
  *(short4v*)&out[(size_t)row * 1024 + tid * 4] = o4;
}

// ---------- row softmax over 2048, IN-PLACE (bf16, short8 vectorized) ----------
__global__ __launch_bounds__(256) void softmax_kernel(
    bf16* __restrict__ sc)
{
  __shared__ float sm[4];
  int tid = threadIdx.x;
  size_t base = ((size_t)blockIdx.y * 2048 + blockIdx.x) * 2048 + (size_t)tid * 8;
  short8 sv = *(const short8*)&sc[base];
  float v[8], m = -1e30f;
  #pragma unroll
  for (int i = 0; i < 8; i++) { v[i] = bf2f(((const bf16*)&sv)[i]); m = fmaxf(m, v[i]); }
  #pragma unroll
  for (int o = 32; o > 0; o >>= 1) m = fmaxf(m, __shfl_down(m, o, 64));
  int wvi = tid >> 6, lnn = tid & 63;
  if (lnn == 0) sm[wvi] = m;
  __syncthreads();
  m = fmaxf(fmaxf(sm[0], sm[1]), fmaxf(sm[2], sm[3]));
  __syncthreads();
  float s = 0.f;
  #pragma unroll
  for (int i = 0; i < 8; i++) { v[i] = __expf(v[i] - m); s += v[i]; }
  #pragma unroll
  for (int o = 32; o > 0; o >>= 1) s += __shfl_down(s, o, 64);
  if (lnn == 0) sm[wvi] = s;
  __syncthreads();
  s = sm[0] + sm[1] + sm[2] + sm[3];
  float inv = 1.0f / s;
  short8 ov;
  #pragma unroll
  for (int i = 0; i < 8; i++)
    ((bf16*)&ov)[i] = __float2bfloat16(v[i] * inv);
  *(short8*)&sc[base] = ov;
}

// ---------------- host ----------------
#define G256(FL, grid_, A_, B_, D_, bias_, res_, K_, lda_, ldb_, ldc_, sc_, zo_)      \
  do {                                                                                \
    (void)hipFuncSetAttribute(reinterpret_cast<const void*>(&gemm256_k<(FL)>),        \
                              hipFuncAttributeMaxDynamicSharedMemorySize, 131072);    \
    hipLaunchKernelGGL((gemm256_k<(FL)>), grid_, dim3(512), 131072, stream,           \
                       A_, B_, D_, bias_, res_, K_, lda_, ldb_, ldc_, sc_, zo_);      \
  } while (0)

extern "C" void kernel_launch(void* const* d_in, const int* in_sizes, int n_in,
                              void* d_out, int out_size, void* d_ws, size_t ws_size,
                              hipStream_t stream) {
  const float* x      = (const float*)d_in[0];
  const float* ln1_w  = (const float*)d_in[1];
  const float* ln1_b  = (const float*)d_in[2];
  const float* qkv_w  = (const float*)d_in[3];
  const float* qkv_b  = (const float*)d_in[4];
  const float* proj_w = (const float*)d_in[5];
  const float* proj_b = (const float*)d_in[6];
  const float* ln2_w  = (const float*)d_in[7];
  const float* ln2_b  = (const float*)d_in[8];
  const float* mlp_w1 = (const float*)d_in[9];
  const float* mlp_b1 = (const float*)d_in[10];
  const float* mlp_w2 = (const float*)d_in[11];
  const float* mlp_b2 = (const float*)d_in[12];
  float* out = (float*)d_out;

  char* ws = (char*)d_ws;
  const size_t MB = 1ull << 20;
  bf16* qkvT  = (bf16*)ws;
  bf16* projT = qkvT + 3 * 1024 * 1024;
  bf16* w1T   = qkvT + 4 * 1024 * 1024;
  bf16* w2T   = qkvT + 6 * 1024 * 1024;
  bf16* xn    = (bf16*)(ws + 16 * MB);
  bf16* qkvb  = (bf16*)(ws + 48 * MB);
  bf16* h1    = qkvb;
  bf16* Vt    = (bf16*)(ws + 144 * MB);

  int CH; bool useVt, x1f32;
  if      (ws_size >= 304 * MB) { CH = 16; useVt = true;  x1f32 = true;  }
  else if (ws_size >= 240 * MB) { CH = 8;  useVt = true;  x1f32 = true;  }
  else if (ws_size >= 208 * MB) { CH = 4;  useVt = true;  x1f32 = false; }
  else                          { CH = 4;  useVt = false; x1f32 = false; }
  char* R = ws + (useVt ? 176 * MB : 144 * MB);
  bf16*  scores = (bf16*)R;
  float* x1f    = (float*)R;   // overlays scores after attention
  bf16*  x1h    = (bf16*)R;

  ZOffs z0 = {};
  const float scale = 0.04419417382415922f;  // 1/sqrt(512)
  dim3 blk(256);

  // 0. weight transpose+convert
  hipLaunchKernelGGL(tconv_kernel, dim3(H3 / 32, C / 32), blk, 0, stream, qkv_w, qkvT, C, H3);
  hipLaunchKernelGGL(tconv_kernel, dim3(C / 32, C / 32), blk, 0, stream, proj_w, projT, C, C);
  hipLaunchKernelGGL(tconv_kernel, dim3(MH / 32, C / 32), blk, 0, stream, mlp_w1, w1T, C, MH);
  hipLaunchKernelGGL(tconv_kernel, dim3(C / 32, MH / 32), blk, 0, stream, mlp_w2, w2T, MH, C);

  // 1. LN1
  hipLaunchKernelGGL((ln_kernel<float>), dim3(MR), blk, 0, stream, x, ln1_w, ln1_b, xn);

  // 2. QKV = xn @ qkv_w + b -> bf16 [16384,3072]
  G256(F_TRANSB | F_BIAS | F_OUTBF16, dim3(H3 / 256, MR / 256, 1),
       xn, qkvT, (void*)qkvb, qkv_b, nullptr, C, C, C, H3, 1.0f, z0);

  // 2b. Vt
  if (useVt)
    hipLaunchKernelGGL(vtrans_kernel, dim3(SEQ / 32, DH / 32, 16), blk, 0, stream, qkvb, Vt);

  // 3. attention in chunks of CH (b,h) pairs
  for (int ch = 0; ch < 16 / CH; ch++) {
    ZOffs zq = {}, zp = {};
    for (int zz = 0; zz < CH; zz++) {
      int bh = ch * CH + zz, b = bh >> 1, hh = bh & 1;
      zq.a[zz] = (long long)b * SEQ * H3 + (long long)hh * DH;          // Q
      zq.b[zz] = (long long)b * SEQ * H3 + C + (long long)hh * DH;      // K
      zq.c[zz] = (long long)zz * SEQ * SEQ;                             // scores
      zp.a[zz] = (long long)zz * SEQ * SEQ;                             // probs
      zp.b[zz] = useVt ? (long long)bh * DH * SEQ                       // Vt slice
                       : (long long)b * SEQ * H3 + 2 * C + (long long)hh * DH;
      zp.c[zz] = (long long)b * SEQ * C + (long long)hh * DH;           // attn_out
    }
    G256(F_TRANSB | F_SCALE | F_OUTBF16, dim3(SEQ / 256, SEQ / 256, CH),
         qkvb, qkvb, (void*)scores, nullptr, nullptr, DH, H3, H3, SEQ, scale, zq);
    hipLaunchKernelGGL(softmax_kernel, dim3(SEQ, CH), blk, 0, stream, scores);
    if (useVt)
      G256(F_TRANSB | F_OUTBF16, dim3(DH / 256, SEQ / 256, CH),
           scores, Vt, (void*)xn, nullptr, nullptr, SEQ, SEQ, SEQ, C, 1.0f, zp);
    else
      hipLaunchKernelGGL((gemm_k<F_OUTBF16>),
                         dim3(DH / TILE, SEQ / TILE, CH), blk, 0, stream,
                         scores, qkvb, (void*)xn, nullptr, nullptr, SEQ, SEQ, H3, C, 1.0f, zp);
  }

  // 4. x1 = attn_out @ proj_w + b + x ; LN2 -> xn2
  if (x1f32) {
    G256(F_TRANSB | F_BIAS | F_RES | F_RESF32, dim3(C / 256, MR / 256, 1),
         xn, projT, (void*)x1f, proj_b, (const void*)x, C, C, C, C, 1.0f, z0);
    hipLaunchKernelGGL((ln_kernel<float>), dim3(MR), blk, 0, stream, x1f, ln2_w, ln2_b, xn);
  } else {
    G256(F_TRANSB | F_BIAS | F_RES | F_RESF32 | F_OUTBF16, dim3(C / 256, MR / 256, 1),
         xn, projT, (void*)x1h, proj_b, (const void*)x, C, C, C, C, 1.0f, z0);
    hipLaunchKernelGGL((ln_kernel<bf16>), dim3(MR), blk, 0, stream, x1h, ln2_w, ln2_b, xn);
  }

  // 5. h1 = gelu(xn2 @ w1 + b1) -> bf16 [16384,2048]
  G256(F_TRANSB | F_BIAS | F_GELU | F_OUTBF16, dim3(MH / 256, MR / 256, 1),
       xn, w1T, (void*)h1, mlp_b1, nullptr, C, C, C, MH, 1.0f, z0);

  // 6. out = x1 + h1 @ w2 + b2 -> fp32 d_out
  if (x1f32) {
    G256(F_TRANSB | F_BIAS | F_RES | F_RESF32, dim3(C / 256, MR / 256, 1),
         h1, w2T, (void*)out, mlp_b2, (const void*)x1f, MH, MH, MH, C, 1.0f, z0);
  } else {
    G256(F_TRANSB | F_BIAS | F_RES, dim3(C / 256, MR / 256, 1),
         h1, w2T, (void*)out, mlp_b2, (const void*)x1h, MH, MH, MH, C, 1.0f, z0);
  }
}

// Round 2
// 765.458 us; speedup vs baseline: 1.2368x; 1.0925x over previous
//
#include <hip/hip_runtime.h>
#include <hip/hip_bf16.h>
#include <math.h>

#define TILE 128
#define BK 32

using short8  = __attribute__((ext_vector_type(8))) short;
using short4v = __attribute__((ext_vector_type(4))) short;
using f32x4   = __attribute__((ext_vector_type(4))) float;
typedef __hip_bfloat16 bf16;

constexpr int BB = 8, SEQ = 2048, C = 1024, H3 = 3072, DH = 512, MH = 2048;
constexpr int MR = BB * SEQ;  // 16384 token rows

enum {
  F_TRANSB = 1,   // B given as [N,K] row-major
  F_GELU   = 2,
  F_RES    = 4,
  F_OUTBF16= 8,
  F_BIAS   = 16,
  F_SCALE  = 32,
  F_RESF32 = 64
};

struct ZOffs { long long a[16]; long long b[16]; long long c[16]; };

__device__ __forceinline__ float bf2f(bf16 h) { return __bfloat162float(h); }

// async global->LDS, 16B per lane; LDS dest is wave-uniform base + lane*16
__device__ __forceinline__ void gload16(const void* g, void* l) {
  __builtin_amdgcn_global_load_lds(
      (const __attribute__((address_space(1))) unsigned int*)g,
      (__attribute__((address_space(3))) unsigned int*)l, 16, 0, 0);
}

// ---------------------------------------------------------------------------
// OLD 128x128 GEMM (kept only for the no-Vt fallback PV path, B=[K,N] layout)
// ---------------------------------------------------------------------------
template<int FLAGS>
__global__ __launch_bounds__(256) void gemm_k(
    const bf16* __restrict__ A,
    const bf16* __restrict__ B,
    void* __restrict__ Dst,
    const float* __restrict__ bias,
    const void* __restrict__ res,
    int K, int lda, int ldb, int ldc,
    float scale, ZOffs zo)
{
  __shared__ __align__(16) unsigned short As[TILE * BK];
  __shared__ __align__(16) unsigned short Bs[TILE * BK];
  const int tid = threadIdx.x;
  const int z = blockIdx.z;
  const int m0 = blockIdx.y * TILE, n0 = blockIdx.x * TILE;
  const bf16* Ab = A + zo.a[z];
  const bf16* Bb = B + zo.b[z];
  const long long coff = zo.c[z];
  const int wave = tid >> 6, lane = tid & 63;
  const int wm = (wave & 1) << 6, wn = (wave >> 1) << 6;
  const int lr = lane & 15, lq = lane >> 4;

  int srow[2], skb[2];
  #pragma unroll
  for (int i = 0; i < 2; i++) {
    int c = tid + (i << 8);
    srow[i] = c >> 2;
    skb[i]  = (c & 3) ^ ((srow[i] >> 1) & 3);
  }
  const bf16* Asrc[2]; const bf16* Bsrc[2] = {nullptr, nullptr};
  #pragma unroll
  for (int i = 0; i < 2; i++)
    Asrc[i] = Ab + (size_t)(m0 + srow[i]) * lda + skb[i] * 8;
  if (FLAGS & F_TRANSB) {
    #pragma unroll
    for (int i = 0; i < 2; i++)
      Bsrc[i] = Bb + (size_t)(n0 + srow[i]) * ldb + skb[i] * 8;
  }

  f32x4 acc[4][4] = {};
  const int swl = (lr >> 1) & 3;

  for (int k0 = 0; k0 < K; k0 += BK) {
    #pragma unroll
    for (int i = 0; i < 2; i++)
      gload16(Asrc[i] + k0, &As[(tid + (i << 8)) * 8]);
    if (FLAGS & F_TRANSB) {
      #pragma unroll
      for (int i = 0; i < 2; i++)
        gload16(Bsrc[i] + k0, &Bs[(tid + (i << 8)) * 8]);
    } else {
      #pragma unroll
      for (int i = 0; i < 2; i++) {
        int c = tid + (i << 8);
        int kk = c >> 4, nn = (c & 15) << 3;
        unsigned short tmp[8];
        *(uint4*)tmp = *(const uint4*)(Bb + (size_t)(k0 + kk) * ldb + n0 + nn);
        #pragma unroll
        for (int j = 0; j < 8; j++) {
          int n = nn + j;
          Bs[n * BK + (((kk >> 3) ^ ((n >> 1) & 3)) << 3) + (kk & 7)] = tmp[j];
        }
      }
    }
    __syncthreads();
    short8 af[4], bfr[4];
    #pragma unroll
    for (int mi = 0; mi < 4; mi++)
      af[mi] = *(const short8*)&As[(wm + mi * 16 + lr) * BK + ((lq ^ swl) << 3)];
    #pragma unroll
    for (int ni = 0; ni < 4; ni++)
      bfr[ni] = *(const short8*)&Bs[(wn + ni * 16 + lr) * BK + ((lq ^ swl) << 3)];
    #pragma unroll
    for (int mi = 0; mi < 4; mi++)
      #pragma unroll
      for (int ni = 0; ni < 4; ni++)
        acc[mi][ni] = __builtin_amdgcn_mfma_f32_16x16x32_bf16(
            af[mi], bfr[ni], acc[mi][ni], 0, 0, 0);
    __syncthreads();
  }

  #pragma unroll
  for (int mi = 0; mi < 4; mi++) {
    #pragma unroll
    for (int ni = 0; ni < 4; ni++) {
      int col = n0 + wn + ni * 16 + lr;
      float bv = (FLAGS & F_BIAS) ? bias[col] : 0.0f;
      #pragma unroll
      for (int r = 0; r < 4; r++) {
        int row = m0 + wm + mi * 16 + lq * 4 + r;
        float v = acc[mi][ni][r];
        if (FLAGS & F_SCALE) v *= scale;
        v += bv;
        if (FLAGS & F_GELU) v = 0.5f * v * (1.0f + erff(v * 0.70710678118654752f));
        if (FLAGS & F_RES) {
          size_t ridx = (size_t)row * ldc + col;
          v += (FLAGS & F_RESF32) ? ((const float*)res)[ridx]
                                  : bf2f(((const bf16*)res)[ridx]);
        }
        size_t idx = (size_t)coff + (size_t)row * ldc + col;
        if (FLAGS & F_OUTBF16) ((bf16*)Dst)[idx] = __float2bfloat16(v);
        else                   ((float*)Dst)[idx] = v;
      }
    }
  }
}

// ---------------------------------------------------------------------------
// 256x256 GEMM, BK=64, 512 threads = 8 waves (2M x 4N), per-wave 128x64 out.
// m201-template schedule: 4 phases/K-tile, 16 MFMA per phase (T3), counted
// vmcnt(8) once per K-tile (T4), setprio around MFMA clusters (T5), XOR slot
// swizzle for conflict-free ds_read_b128 (T2), XCD-aware block swizzle (T1).
// Deep prefetch with 2 buffers via HALF-TILE LIVENESS: tile t+2's half-tiles
// are staged into tile t's buffer right after each half dies:
//   Ah0 = A rows {0-63,128-191}   read only at P0  -> restaged at P1
//   Bh0 = B rows {0-31,64-95,128-159,192-223} read at P0 -> restaged at P1
//   Bh1 = odd 32-stripes          read only at P1  -> restaged at P2
//   Ah1 = A rows {64-127,192-255} read only at P2  -> restaged at P3
// bfr(nh=0) frags stay live in regs P0->P3 so P3 needs no ds_reads.
// Requires F_TRANSB, M,N % 256 == 0, K % 128 == 0 (nt >= 2).
// ---------------------------------------------------------------------------
template<int FLAGS>
__global__ __launch_bounds__(512, 2) void gemm256_k(
    const bf16* __restrict__ A,
    const bf16* __restrict__ B,
    void* __restrict__ Dst,
    const float* __restrict__ bias,
    const void* __restrict__ res,
    int K, int lda, int ldb, int ldc,
    float scale, ZOffs zo)
{
  static_assert(FLAGS & F_TRANSB, "gemm256_k requires B^T layout");
  extern __shared__ __align__(16) unsigned short smem[];  // [A0|A1|B0|B1] 4x32KB

  const int tid = threadIdx.x;
  const int z = blockIdx.z;

  // T1: bijective XCD swizzle over (bx,by); all grids have nwg % 8 == 0.
  const int gx = gridDim.x;
  const int nwg = gx * gridDim.y;
  const int wg = blockIdx.y * gx + blockIdx.x;
  const int cpx = nwg >> 3;
  const int swz = (wg & 7) * cpx + (wg >> 3);
  const int m0 = (swz / gx) * 256, n0 = (swz % gx) * 256;

  const bf16* Ab = A + zo.a[z];
  const bf16* Bb = B + zo.b[z];
  const long long coff = zo.c[z];
  const int wave = tid >> 6, lane = tid & 63;
  const int wm = wave >> 2, wn = wave & 3;         // 2 x 4 wave grid
  const int lr = lane & 15, lq = lane >> 4;
  const int r7 = lr & 7;
  const int sk0 = (lq ^ r7) << 3;                  // kk=0 slot (ushort idx)
  const int sk1 = ((4 + lq) ^ r7) << 3;            // kk=1 slot
  const int rowA = (wm * 128 + lr) * 64;           // base in A buf (ushorts)
  const int rowB = (wn * 64 + lr) * 64;            // base in B buf

  // staging geometry: 8 gloads/thread per K-tile (A: 4, B: 4)
  const int t8 = tid >> 3, s8 = tid & 7;
  const int sslot = (s8 ^ (t8 & 7)) << 3;          // pre-swizzled source k-slot
  const bf16* srcA = Ab + (size_t)(m0 + t8) * lda + sslot;
  const int rB0 = (t8 & 31) + ((t8 >> 5) << 6);
  const bf16* srcB = Bb + (size_t)(n0 + rB0) * ldb + sslot;
  const int dA0 = tid * 8;                         // LDS dest (ushort idx)
  const int dB0 = rB0 * 64 + s8 * 8;

  const int nt = K >> 6;                           // K-tiles of 64

#define SA(h_, ks_, Ad_)                                                       \
  do {                                                                         \
    gload16(srcA + (size_t)((h_) * 64) * lda + (ks_),                          \
            (Ad_) + dA0 + (h_) * 4096);                                        \
    gload16(srcA + (size_t)((h_) * 64 + 128) * lda + (ks_),                    \
            (Ad_) + dA0 + (h_) * 4096 + 8192);                                 \
  } while (0)
#define SB(h_, ks_, Bd_)                                                       \
  do {                                                                         \
    gload16(srcB + (size_t)((h_) * 32) * ldb + (ks_),                          \
            (Bd_) + dB0 + (h_) * 2048);                                        \
    gload16(srcB + (size_t)((h_) * 32 + 128) * ldb + (ks_),                    \
            (Bd_) + dB0 + (h_) * 2048 + 8192);                                 \
  } while (0)

  // prologue: fully stage tiles 0 and 1
  {
    const int npro = nt < 2 ? nt : 2;
    for (int t = 0; t < npro; ++t) {
      unsigned short* Ad = smem + (t & 1) * 16384;
      unsigned short* Bd = smem + 32768 + (t & 1) * 16384;
      const int ks = t * 64;
      SA(0, ks, Ad); SA(1, ks, Ad); SB(0, ks, Bd); SB(1, ks, Bd);
    }
  }

  f32x4 acc[8][4] = {};
  short8 af0[4], af1[4];                 // A frags for current mh (kk=0/1)
  short8 bA0[2], bA1[2];                 // B frags nh=0 (live P0 -> P3)
  short8 bB0[2], bB1[2];                 // B frags nh=1

#define RD_AF(mh_)                                                             \
  _Pragma("unroll")                                                            \
  for (int m_ = 0; m_ < 4; ++m_) {                                             \
    af0[m_] = *(const short8*)&At[rowA + ((mh_) * 64 + m_ * 16) * 64 + sk0];   \
    af1[m_] = *(const short8*)&At[rowA + ((mh_) * 64 + m_ * 16) * 64 + sk1];   \
  }
#define RD_BF(nh_, b0_, b1_)                                                   \
  _Pragma("unroll")                                                            \
  for (int n_ = 0; n_ < 2; ++n_) {                                             \
    b0_[n_] = *(const short8*)&Bt[rowB + ((nh_) * 32 + n_ * 16) * 64 + sk0];   \
    b1_[n_] = *(const short8*)&Bt[rowB + ((nh_) * 32 + n_ * 16) * 64 + sk1];   \
  }
#define MM(mh_, nh_, b0_, b1_)                                                 \
  __builtin_amdgcn_s_setprio(1);                                               \
  _Pragma("unroll")                                                            \
  for (int m_ = 0; m_ < 4; ++m_)                                               \
    _Pragma("unroll")                                                          \
    for (int n_ = 0; n_ < 2; ++n_) {                                           \
      acc[(mh_) * 4 + m_][(nh_) * 2 + n_] =                                    \
          __builtin_amdgcn_mfma_f32_16x16x32_bf16(                             \
              af0[m_], b0_[n_], acc[(mh_) * 4 + m_][(nh_) * 2 + n_], 0, 0, 0); \
      acc[(mh_) * 4 + m_][(nh_) * 2 + n_] =                                    \
          __builtin_amdgcn_mfma_f32_16x16x32_bf16(                             \
              af1[m_], b1_[n_], acc[(mh_) * 4 + m_][(nh_) * 2 + n_], 0, 0, 0); \
    }                                                                          \
  __builtin_amdgcn_s_setprio(0);

  for (int t = 0; t < nt; ++t) {
    // K-tile boundary: counted wait (T4). Outstanding = tile t's 8 + tile
    // t+1's 8 at most; vmcnt(8) retires tile t's, keeps t+1's in flight.
    if (t == nt - 1) asm volatile("s_waitcnt vmcnt(0)" ::: "memory");
    else             asm volatile("s_waitcnt vmcnt(8)" ::: "memory");
    __builtin_amdgcn_s_barrier();

    const unsigned short* At = smem + (t & 1) * 16384;
    const unsigned short* Bt = smem + 32768 + (t & 1) * 16384;
    unsigned short* Ad = smem + (t & 1) * 16384;     // stage tile t+2 here
    unsigned short* Bd = smem + 32768 + (t & 1) * 16384;
    const bool st = (t + 2) < nt;
    const int ks = (t + 2) * 64;

    // P0: quadrant (0,0) — 12 ds_reads
    RD_AF(0);
    RD_BF(0, bA0, bA1);
    __builtin_amdgcn_s_barrier();
    MM(0, 0, bA0, bA1);
    __builtin_amdgcn_s_barrier();

    // P1: (0,1) — Ah0/Bh0 of this buffer are dead; stage t+2's
    RD_BF(1, bB0, bB1);
    if (st) { SA(0, ks, Ad); SB(0, ks, Bd); }
    __builtin_amdgcn_s_barrier();
    MM(0, 1, bB0, bB1);
    __builtin_amdgcn_s_barrier();

    // P2: (1,1) — Bh1 dead after P1's reads
    RD_AF(1);
    if (st) { SB(1, ks, Bd); }
    __builtin_amdgcn_s_barrier();
    MM(1, 1, bB0, bB1);
    __builtin_amdgcn_s_barrier();

    // P3: (1,0) — no ds_reads (bA0/bA1 kept in regs); Ah1 dead after P2
    if (st) { SA(1, ks, Ad); }
    MM(1, 0, bA0, bA1);
    // loop-top vmcnt + barrier closes the tile
  }

#undef SA
#undef SB
#undef RD_AF
#undef RD_BF
#undef MM

  // epilogue: C/D layout col=lane&15, row=quad*4+reg
  const int colBase = n0 + wn * 64 + lr;
  float bv[4];
  #pragma unroll
  for (int n = 0; n < 4; ++n)
    bv[n] = (FLAGS & F_BIAS) ? bias[colBase + n * 16] : 0.0f;
  #pragma unroll
  for (int m = 0; m < 8; ++m) {
    #pragma unroll
    for (int n = 0; n < 4; ++n) {
      const int col = colBase + n * 16;
      #pragma unroll
      for (int r = 0; r < 4; ++r) {
        const int row = m0 + wm * 128 + m * 16 + lq * 4 + r;
        float v = acc[m][n][r];
        if (FLAGS & F_SCALE) v *= scale;
        v += bv[n];
        if (FLAGS & F_GELU) v = 0.5f * v * (1.0f + erff(v * 0.70710678118654752f));
        if (FLAGS & F_RES) {
          size_t ridx = (size_t)row * ldc + col;
          v += (FLAGS & F_RESF32) ? ((const float*)res)[ridx]
                                  : bf2f(((const bf16*)res)[ridx]);
        }
        size_t idx = (size_t)coff + (size_t)row * ldc + col;
        if (FLAGS & F_OUTBF16) ((bf16*)Dst)[idx] = __float2bfloat16(v);
        else                   ((float*)Dst)[idx] = v;
      }
    }
  }
}

// ---------- weight transpose+convert: src fp32 [K,N] -> dst bf16 [N,K] ----------
__global__ __launch_bounds__(256) void tconv_kernel(
    const float* __restrict__ src, bf16* __restrict__ dst, int K, int N)
{
  __shared__ float t[32][33];
  int n0 = blockIdx.x * 32, k0 = blockIdx.y * 32;
  int c = threadIdx.x & 31, r = threadIdx.x >> 5;
  #pragma unroll
  for (int i = 0; i < 4; i++)
    t[r + i * 8][c] = src[(size_t)(k0 + r + i * 8) * N + n0 + c];
  __syncthreads();
  #pragma unroll
  for (int i = 0; i < 4; i++)
    dst[(size_t)(n0 + r + i * 8) * K + k0 + c] = __float2bfloat16(t[c][r + i * 8]);
}

// ---------- V transpose: qkv V-slice [n][d] -> Vt[bh][d][n] (bf16) ----------
__global__ __launch_bounds__(256) void vtrans_kernel(
    const bf16* __restrict__ qkv, bf16* __restrict__ vt)
{
  __shared__ unsigned short t[32][33];
  int bh = blockIdx.z, b = bh >> 1, h = bh & 1;
  int n0 = blockIdx.x * 32, d0 = blockIdx.y * 32;
  int c = threadIdx.x & 31, r = threadIdx.x >> 5;
  const bf16* src = qkv + (size_t)b * SEQ * H3 + 2 * C + (size_t)h * DH;
  #pragma unroll
  for (int i = 0; i < 4; i++)
    t[r + i * 8][c] = *(const unsigned short*)&src[(size_t)(n0 + r + i * 8) * H3 + d0 + c];
  __syncthreads();
  bf16* dst = vt + ((size_t)bh * DH + d0) * SEQ + n0;
  #pragma unroll
  for (int i = 0; i < 4; i++)
    *(unsigned short*)&dst[(size_t)(r + i * 8) * SEQ + c] = t[c][r + i * 8];
}

// ---------- vectorized loads for LN ----------
__device__ __forceinline__ void ld4(const float* p, float v[4]) {
  const float4 t = *(const float4*)p;
  v[0] = t.x; v[1] = t.y; v[2] = t.z; v[3] = t.w;
}
__device__ __forceinline__ void ld4(const bf16* p, float v[4]) {
  short4v t = *(const short4v*)p;
  #pragma unroll
  for (int i = 0; i < 4; ++i) v[i] = bf2f(((const bf16*)&t)[i]);
}

// ---------- LayerNorm over C=1024, one block per row (vectorized) ----------
template<typename T>
__global__ __launch_bounds__(256) void ln_kernel(
    const T* __restrict__ x,
    const float* __restrict__ w,
    const float* __restrict__ b,
    bf16* __restrict__ out)
{
  __shared__ float sm[4], sm2[4];
  int row = blockIdx.x, tid = threadIdx.x;
  float v[4];
  ld4(x + (size_t)row * 1024 + tid * 4, v);
  float s  = v[0] + v[1] + v[2] + v[3];
  float sq = v[0]*v[0] + v[1]*v[1] + v[2]*v[2] + v[3]*v[3];
  #pragma unroll
  for (int o = 32; o > 0; o >>= 1) {
    s  += __shfl_down(s, o, 64);
    sq += __shfl_down(sq, o, 64);
  }
  int wvi = tid >> 6, lnn = tid & 63;
  if (lnn == 0) { sm[wvi] = s; sm2[wvi] = sq; }
  __syncthreads();
  s  = sm[0] + sm[1] + sm[2] + sm[3];
  sq = sm2[0] + sm2[1] + sm2[2] + sm2[3];
  float mean = s * (1.0f / 1024.0f);
  float var  = sq * (1.0f / 1024.0f) - mean * mean;
  float rs = rsqrtf(var + 1e-5f);
  float wv4[4], bv4[4];
  ld4(w + tid * 4, wv4);
  ld4(b + tid * 4, bv4);
  short4v o4;
  #pragma unroll
  for (int i = 0; i < 4; ++i)
    ((bf16*)&o4)[i] = __float2bfloat16((v[i] - mean) * rs * wv4[i] + bv4[i]);
  *(short4v*)&out[(size_t)row * 1024 + tid * 4] = o4;
}

// ---------- row softmax over 2048, IN-PLACE (bf16, short8 vectorized) ----------
__global__ __launch_bounds__(256) void softmax_kernel(
    bf16* __restrict__ sc)
{
  __shared__ float sm[4];
  int tid = threadIdx.x;
  size_t base = ((size_t)blockIdx.y * 2048 + blockIdx.x) * 2048 + (size_t)tid * 8;
  short8 sv = *(const short8*)&sc[base];
  float v[8], m = -1e30f;
  #pragma unroll
  for (int i = 0; i < 8; i++) { v[i] = bf2f(((const bf16*)&sv)[i]); m = fmaxf(m, v[i]); }
  #pragma unroll
  for (int o = 32; o > 0; o >>= 1) m = fmaxf(m, __shfl_down(m, o, 64));
  int wvi = tid >> 6, lnn = tid & 63;
  if (lnn == 0) sm[wvi] = m;
  __syncthreads();
  m = fmaxf(fmaxf(sm[0], sm[1]), fmaxf(sm[2], sm[3]));
  __syncthreads();
  float s = 0.f;
  #pragma unroll
  for (int i = 0; i < 8; i++) { v[i] = __expf(v[i] - m); s += v[i]; }
  #pragma unroll
  for (int o = 32; o > 0; o >>= 1) s += __shfl_down(s, o, 64);
  if (lnn == 0) sm[wvi] = s;
  __syncthreads();
  s = sm[0] + sm[1] + sm[2] + sm[3];
  float inv = 1.0f / s;
  short8 ov;
  #pragma unroll
  for (int i = 0; i < 8; i++)
    ((bf16*)&ov)[i] = __float2bfloat16(v[i] * inv);
  *(short8*)&sc[base] = ov;
}

// ---------------- host ----------------
#define G256(FL, grid_, A_, B_, D_, bias_, res_, K_, lda_, ldb_, ldc_, sc_, zo_)      \
  do {                                                                                \
    (void)hipFuncSetAttribute(reinterpret_cast<const void*>(&gemm256_k<(FL)>),        \
                              hipFuncAttributeMaxDynamicSharedMemorySize, 131072);    \
    hipLaunchKernelGGL((gemm256_k<(FL)>), grid_, dim3(512), 131072, stream,           \
                       A_, B_, D_, bias_, res_, K_, lda_, ldb_, ldc_, sc_, zo_);      \
  } while (0)

extern "C" void kernel_launch(void* const* d_in, const int* in_sizes, int n_in,
                              void* d_out, int out_size, void* d_ws, size_t ws_size,
                              hipStream_t stream) {
  const float* x      = (const float*)d_in[0];
  const float* ln1_w  = (const float*)d_in[1];
  const float* ln1_b  = (const float*)d_in[2];
  const float* qkv_w  = (const float*)d_in[3];
  const float* qkv_b  = (const float*)d_in[4];
  const float* proj_w = (const float*)d_in[5];
  const float* proj_b = (const float*)d_in[6];
  const float* ln2_w  = (const float*)d_in[7];
  const float* ln2_b  = (const float*)d_in[8];
  const float* mlp_w1 = (const float*)d_in[9];
  const float* mlp_b1 = (const float*)d_in[10];
  const float* mlp_w2 = (const float*)d_in[11];
  const float* mlp_b2 = (const float*)d_in[12];
  float* out = (float*)d_out;

  char* ws = (char*)d_ws;
  const size_t MB = 1ull << 20;
  bf16* qkvT  = (bf16*)ws;
  bf16* projT = qkvT + 3 * 1024 * 1024;
  bf16* w1T   = qkvT + 4 * 1024 * 1024;
  bf16* w2T   = qkvT + 6 * 1024 * 1024;
  bf16* xn    = (bf16*)(ws + 16 * MB);
  bf16* qkvb  = (bf16*)(ws + 48 * MB);
  bf16* h1    = qkvb;
  bf16* Vt    = (bf16*)(ws + 144 * MB);

  int CH; bool useVt, x1f32;
  if      (ws_size >= 304 * MB) { CH = 16; useVt = true;  x1f32 = true;  }
  else if (ws_size >= 240 * MB) { CH = 8;  useVt = true;  x1f32 = true;  }
  else if (ws_size >= 208 * MB) { CH = 4;  useVt = true;  x1f32 = false; }
  else                          { CH = 4;  useVt = false; x1f32 = false; }
  char* R = ws + (useVt ? 176 * MB : 144 * MB);
  bf16*  scores = (bf16*)R;
  float* x1f    = (float*)R;   // overlays scores after attention
  bf16*  x1h    = (bf16*)R;

  ZOffs z0 = {};
  const float scale = 0.04419417382415922f;  // 1/sqrt(512)
  dim3 blk(256);

  // 0. weight transpose+convert
  hipLaunchKernelGGL(tconv_kernel, dim3(H3 / 32, C / 32), blk, 0, stream, qkv_w, qkvT, C, H3);
  hipLaunchKernelGGL(tconv_kernel, dim3(C / 32, C / 32), blk, 0, stream, proj_w, projT, C, C);
  hipLaunchKernelGGL(tconv_kernel, dim3(MH / 32, C / 32), blk, 0, stream, mlp_w1, w1T, C, MH);
  hipLaunchKernelGGL(tconv_kernel, dim3(C / 32, MH / 32), blk, 0, stream, mlp_w2, w2T, MH, C);

  // 1. LN1
  hipLaunchKernelGGL((ln_kernel<float>), dim3(MR), blk, 0, stream, x, ln1_w, ln1_b, xn);

  // 2. QKV = xn @ qkv_w + b -> bf16 [16384,3072]
  G256(F_TRANSB | F_BIAS | F_OUTBF16, dim3(H3 / 256, MR / 256, 1),
       xn, qkvT, (void*)qkvb, qkv_b, nullptr, C, C, C, H3, 1.0f, z0);

  // 2b. Vt
  if (useVt)
    hipLaunchKernelGGL(vtrans_kernel, dim3(SEQ / 32, DH / 32, 16), blk, 0, stream, qkvb, Vt);

  // 3. attention in chunks of CH (b,h) pairs
  for (int ch = 0; ch < 16 / CH; ch++) {
    ZOffs zq = {}, zp = {};
    for (int zz = 0; zz < CH; zz++) {
      int bh = ch * CH + zz, b = bh >> 1, hh = bh & 1;
      zq.a[zz] = (long long)b * SEQ * H3 + (long long)hh * DH;          // Q
      zq.b[zz] = (long long)b * SEQ * H3 + C + (long long)hh * DH;      // K
      zq.c[zz] = (long long)zz * SEQ * SEQ;                             // scores
      zp.a[zz] = (long long)zz * SEQ * SEQ;                             // probs
      zp.b[zz] = useVt ? (long long)bh * DH * SEQ                       // Vt slice
                       : (long long)b * SEQ * H3 + 2 * C + (long long)hh * DH;
      zp.c[zz] = (long long)b * SEQ * C + (long long)hh * DH;           // attn_out
    }
    G256(F_TRANSB | F_SCALE | F_OUTBF16, dim3(SEQ / 256, SEQ / 256, CH),
         qkvb, qkvb, (void*)scores, nullptr, nullptr, DH, H3, H3, SEQ, scale, zq);
    hipLaunchKernelGGL(softmax_kernel, dim3(SEQ, CH), blk, 0, stream, scores);
    if (useVt)
      G256(F_TRANSB | F_OUTBF16, dim3(DH / 256, SEQ / 256, CH),
           scores, Vt, (void*)xn, nullptr, nullptr, SEQ, SEQ, SEQ, C, 1.0f, zp);
    else
      hipLaunchKernelGGL((gemm_k<F_OUTBF16>),
                         dim3(DH / TILE, SEQ / TILE, CH), blk, 0, stream,
                         scores, qkvb, (void*)xn, nullptr, nullptr, SEQ, SEQ, H3, C, 1.0f, zp);
  }

  // 4. x1 = attn_out @ proj_w + b + x ; LN2 -> xn2
  if (x1f32) {
    G256(F_TRANSB | F_BIAS | F_RES | F_RESF32, dim3(C / 256, MR / 256, 1),
         xn, projT, (void*)x1f, proj_b, (const void*)x, C, C, C, C, 1.0f, z0);
    hipLaunchKernelGGL((ln_kernel<float>), dim3(MR), blk, 0, stream, x1f, ln2_w, ln2_b, xn);
  } else {
    G256(F_TRANSB | F_BIAS | F_RES | F_RESF32 | F_OUTBF16, dim3(C / 256, MR / 256, 1),
         xn, projT, (void*)x1h, proj_b, (const void*)x, C, C, C, C, 1.0f, z0);
    hipLaunchKernelGGL((ln_kernel<bf16>), dim3(MR), blk, 0, stream, x1h, ln2_w, ln2_b, xn);
  }

  // 5. h1 = gelu(xn2 @ w1 + b1) -> bf16 [16384,2048]
  G256(F_TRANSB | F_BIAS | F_GELU | F_OUTBF16, dim3(MH / 256, MR / 256, 1),
       xn, w1T, (void*)h1, mlp_b1, nullptr, C, C, C, MH, 1.0f, z0);

  // 6. out = x1 + h1 @ w2 + b2 -> fp32 d_out
  if (x1f32) {
    G256(F_TRANSB | F_BIAS | F_RES | F_RESF32, dim3(C / 256, MR / 256, 1),
         h1, w2T, (void*)out, mlp_b2, (const void*)x1f, MH, MH, MH, C, 1.0f, z0);
  } else {
    G256(F_TRANSB | F_BIAS | F_RES, dim3(C / 256, MR / 256, 1),
         h1, w2T, (void*)out, mlp_b2, (const void*)x1h, MH, MH, MH, C, 1.0f, z0);
  }
}